// Round 1
// baseline (520.432 us; speedup 1.0000x reference)
//
#include <hip/hip_runtime.h>
#include <math.h>

#define N_NODES 50000
#define N_EDGES 800000
#define ET (N_EDGES + N_NODES)
#define IN_F 128
#define TDIM 64
#define HEADS 4
#define C0 64
#define C1 16
#define HC0 (HEADS * C0) /* 256 */
#define HC1 (HEADS * C1) /* 64  */
#define SLOPE 0.2f

// ---------------------------------------------------------------------------
// Pre-contract lin_edge with att_edge: v[td][h] = sum_c lin_e[td][h*C+c]*att_e[h][c]
// Also loop_alpha[h] = sum_td v[td][h]  (self-loop edge feature is all-ones)
__global__ void k_tables(const float* __restrict__ lin_e0, const float* __restrict__ att_e0,
                         const float* __restrict__ lin_e1, const float* __restrict__ att_e1,
                         float* __restrict__ v0, float* __restrict__ v1,
                         float* __restrict__ l0, float* __restrict__ l1) {
    int tid = threadIdx.x;           // 256 threads
    int td = tid >> 2, h = tid & 3;
    float s0 = 0.f;
    for (int c = 0; c < C0; ++c) s0 += lin_e0[td * HC0 + h * C0 + c] * att_e0[h * C0 + c];
    v0[td * 4 + h] = s0;
    float s1 = 0.f;
    for (int c = 0; c < C1; ++c) s1 += lin_e1[td * HC1 + h * C1 + c] * att_e1[h * C1 + c];
    v1[td * 4 + h] = s1;
    __syncthreads();
    if (tid < 4) {
        float a0 = 0.f, a1 = 0.f;
        for (int t = 0; t < TDIM; ++t) { a0 += v0[t * 4 + tid]; a1 += v1[t * 4 + tid]; }
        l0[tid] = a0;
        l1[tid] = a1;
    }
}

// ---------------------------------------------------------------------------
// Per real edge: ef[td] = |cos(ts*w[td]+b[td])| ; ae[t][h] = sum_td ef[td]*v[td][h]
__global__ void k_timeenc(const float* __restrict__ ts, const float* __restrict__ tw,
                          const float* __restrict__ tb, const float* __restrict__ v0,
                          const float* __restrict__ v1, float* __restrict__ ae0,
                          float* __restrict__ ae1) {
    __shared__ float sw[TDIM], sb[TDIM], sv0[TDIM * 4], sv1[TDIM * 4];
    int tid = threadIdx.x;
    if (tid < TDIM) { sw[tid] = tw[tid]; sb[tid] = tb[tid]; }
    sv0[tid] = v0[tid];
    sv1[tid] = v1[tid];
    __syncthreads();
    int t = blockIdx.x * blockDim.x + tid;
    if (t >= N_EDGES) return;
    float time = ts[t];
    float a00 = 0, a01 = 0, a02 = 0, a03 = 0, a10 = 0, a11 = 0, a12 = 0, a13 = 0;
    for (int d = 0; d < TDIM; ++d) {
        float f = fabsf(cosf(time * sw[d] + sb[d]));
        a00 += f * sv0[d * 4 + 0];
        a01 += f * sv0[d * 4 + 1];
        a02 += f * sv0[d * 4 + 2];
        a03 += f * sv0[d * 4 + 3];
        a10 += f * sv1[d * 4 + 0];
        a11 += f * sv1[d * 4 + 1];
        a12 += f * sv1[d * 4 + 2];
        a13 += f * sv1[d * 4 + 3];
    }
    ((float4*)ae0)[t] = make_float4(a00, a01, a02, a03);
    ((float4*)ae1)[t] = make_float4(a10, a11, a12, a13);
}

// ---------------------------------------------------------------------------
// CSR build over destination node (shared by both layers)
__global__ void k_zero(int* __restrict__ p, int n) {
    int i = blockIdx.x * blockDim.x + threadIdx.x;
    if (i < n) p[i] = 0;
}

__global__ void k_count(const int* __restrict__ ei, int* __restrict__ deg) {
    int t = blockIdx.x * blockDim.x + threadIdx.x;
    if (t >= ET) return;
    int d = (t < N_EDGES) ? ei[N_EDGES + t] : (t - N_EDGES);
    atomicAdd(&deg[d], 1);
}

__global__ void k_scan_block(const int* __restrict__ deg, int* __restrict__ rowptr,
                             int* __restrict__ blocksum, int n) {
    __shared__ int buf[256];
    int tid = threadIdx.x, i = blockIdx.x * 256 + tid;
    int v = (i < n) ? deg[i] : 0;
    buf[tid] = v;
    __syncthreads();
    for (int off = 1; off < 256; off <<= 1) {
        int t = (tid >= off) ? buf[tid - off] : 0;
        __syncthreads();
        buf[tid] += t;
        __syncthreads();
    }
    if (i < n) rowptr[i + 1] = buf[tid];
    if (tid == 255) blocksum[blockIdx.x] = buf[255];
}

__global__ void k_scan_top(const int* __restrict__ blocksum, int* __restrict__ blockoff, int nb) {
    __shared__ int buf[256];
    int tid = threadIdx.x;
    int v = (tid < nb) ? blocksum[tid] : 0;
    buf[tid] = v;
    __syncthreads();
    for (int off = 1; off < 256; off <<= 1) {
        int t = (tid >= off) ? buf[tid - off] : 0;
        __syncthreads();
        buf[tid] += t;
        __syncthreads();
    }
    if (tid < nb) blockoff[tid] = buf[tid] - v;  // exclusive
}

__global__ void k_scan_add(int* __restrict__ rowptr, const int* __restrict__ blockoff, int n) {
    int i = blockIdx.x * 256 + threadIdx.x;
    if (i < n) rowptr[i + 1] += blockoff[blockIdx.x];
    if (i == 0) rowptr[0] = 0;
}

__global__ void k_cursor(const int* __restrict__ rowptr, int* __restrict__ cursor, int n) {
    int i = blockIdx.x * 256 + threadIdx.x;
    if (i < n) cursor[i] = rowptr[i];
}

__global__ void k_scatter(const int* __restrict__ ei, int* __restrict__ cursor,
                          int* __restrict__ eidx, int* __restrict__ esrc) {
    int t = blockIdx.x * blockDim.x + threadIdx.x;
    if (t >= ET) return;
    int d, s;
    if (t < N_EDGES) {
        s = ei[t];
        d = ei[N_EDGES + t];
    } else {
        s = t - N_EDGES;
        d = t - N_EDGES;
    }
    int p = atomicAdd(&cursor[d], 1);
    eidx[p] = t;
    esrc[p] = s;
}

// ---------------------------------------------------------------------------
// Simple f32 tiled GEMM  C[M,Nc] = A[M,K] @ B[K,Nc];  K%16==0, Nc%64==0
__global__ __launch_bounds__(256) void k_gemm(const float* __restrict__ A,
                                              const float* __restrict__ B, float* __restrict__ C,
                                              int M, int K, int Nc) {
    const int BM = 128, BN = 64, BK = 16;
    __shared__ float As[BK][BM + 4];
    __shared__ float Bs[BK][BN + 4];
    int tid = threadIdx.x;
    int m0 = blockIdx.y * BM, n0 = blockIdx.x * BN;
    int ty = tid >> 4, tx = tid & 15;
    float acc[8][4];
#pragma unroll
    for (int i = 0; i < 8; ++i)
#pragma unroll
        for (int j = 0; j < 4; ++j) acc[i][j] = 0.f;

    int ar = tid >> 2, ac = (tid & 3) << 2;
    int br = tid >> 4, bc = (tid & 15) << 2;

    for (int k0 = 0; k0 < K; k0 += BK) {
#pragma unroll
        for (int half = 0; half < 2; ++half) {
            int row = ar + half * 64;
            float4 va = make_float4(0.f, 0.f, 0.f, 0.f);
            if (m0 + row < M) va = *(const float4*)(A + (size_t)(m0 + row) * K + k0 + ac);
            As[ac + 0][row] = va.x;
            As[ac + 1][row] = va.y;
            As[ac + 2][row] = va.z;
            As[ac + 3][row] = va.w;
        }
        float4 vb = *(const float4*)(B + (size_t)(k0 + br) * Nc + n0 + bc);
        Bs[br][bc + 0] = vb.x;
        Bs[br][bc + 1] = vb.y;
        Bs[br][bc + 2] = vb.z;
        Bs[br][bc + 3] = vb.w;
        __syncthreads();
#pragma unroll
        for (int kk = 0; kk < BK; ++kk) {
            float a[8], b[4];
#pragma unroll
            for (int i = 0; i < 8; ++i) a[i] = As[kk][ty * 8 + i];
#pragma unroll
            for (int j = 0; j < 4; ++j) b[j] = Bs[kk][tx * 4 + j];
#pragma unroll
            for (int i = 0; i < 8; ++i)
#pragma unroll
                for (int j = 0; j < 4; ++j) acc[i][j] += a[i] * b[j];
        }
        __syncthreads();
    }
#pragma unroll
    for (int i = 0; i < 8; ++i) {
        int row = m0 + ty * 8 + i;
        if (row < M) {
#pragma unroll
            for (int j = 0; j < 4; ++j) C[(size_t)row * Nc + n0 + tx * 4 + j] = acc[i][j];
        }
    }
}

// ---------------------------------------------------------------------------
// Per-node attention score dots: s_src[n][h] = sum_c h[n][h][c]*a_src[h][c]
__global__ void k_scores0(const float* __restrict__ h0, const float* __restrict__ a_src,
                          const float* __restrict__ a_dst, float* __restrict__ s_src,
                          float* __restrict__ s_dst) {
    int gid = blockIdx.x * blockDim.x + threadIdx.x;
    int n = gid >> 6, lane = threadIdx.x & 63;
    if (n >= N_NODES) return;
    const float* hr = h0 + (size_t)n * HC0;
#pragma unroll
    for (int h = 0; h < 4; ++h) {
        float x = hr[h * 64 + lane];
        float ps = x * a_src[h * 64 + lane];
        float pd = x * a_dst[h * 64 + lane];
        for (int m = 1; m < 64; m <<= 1) {
            ps += __shfl_xor(ps, m);
            pd += __shfl_xor(pd, m);
        }
        if (lane == 0) {
            s_src[n * 4 + h] = ps;
            s_dst[n * 4 + h] = pd;
        }
    }
}

__global__ void k_scores1(const float* __restrict__ h1, const float* __restrict__ a_src,
                          const float* __restrict__ a_dst, float* __restrict__ s_src,
                          float* __restrict__ s_dst) {
    int gid = blockIdx.x * blockDim.x + threadIdx.x;
    int n = gid >> 6, lane = threadIdx.x & 63;
    if (n >= N_NODES) return;
    float x = h1[(size_t)n * HC1 + lane];
    float ps = x * a_src[lane];
    float pd = x * a_dst[lane];
    for (int m = 1; m < 16; m <<= 1) {
        ps += __shfl_xor(ps, m);
        pd += __shfl_xor(pd, m);
    }
    if ((lane & 15) == 0) {
        s_src[n * 4 + (lane >> 4)] = ps;
        s_dst[n * 4 + (lane >> 4)] = pd;
    }
}

// ---------------------------------------------------------------------------
// Fused softmax + aggregation, one wave per destination node.
// Softmax max-subtraction dropped (mathematically cancels; |alpha| small).
__global__ __launch_bounds__(256) void k_agg0(
    const float* __restrict__ h0, const float* __restrict__ s_src,
    const float* __restrict__ s_dst, const float* __restrict__ ae0, const float* __restrict__ l0,
    const int* __restrict__ rowptr, const int* __restrict__ eidx, const int* __restrict__ esrc,
    const float* __restrict__ bias, float* __restrict__ out) {
    int gid = blockIdx.x * blockDim.x + threadIdx.x;
    int n = gid >> 6, lane = threadIdx.x & 63;
    if (n >= N_NODES) return;
    float4 sd = *(const float4*)(s_dst + n * 4);
    float4 la = *(const float4*)l0;
    float acc0 = 0, acc1 = 0, acc2 = 0, acc3 = 0;
    float ss0 = 0, ss1 = 0, ss2 = 0, ss3 = 0;
    int p1 = rowptr[n + 1];
    for (int p = rowptr[n]; p < p1; ++p) {
        int t = eidx[p], s = esrc[p];
        float4 as = *(const float4*)(s_src + (size_t)s * 4);
        float4 ae = (t < N_EDGES) ? *(const float4*)(ae0 + (size_t)t * 4) : la;
        float a0 = as.x + sd.x + ae.x;
        float a1 = as.y + sd.y + ae.y;
        float a2 = as.z + sd.z + ae.z;
        float a3 = as.w + sd.w + ae.w;
        a0 = a0 >= 0.f ? a0 : SLOPE * a0;
        a1 = a1 >= 0.f ? a1 : SLOPE * a1;
        a2 = a2 >= 0.f ? a2 : SLOPE * a2;
        a3 = a3 >= 0.f ? a3 : SLOPE * a3;
        float e0 = expf(a0), e1 = expf(a1), e2 = expf(a2), e3 = expf(a3);
        const float* hr = h0 + (size_t)s * HC0;
        acc0 += e0 * hr[lane];
        acc1 += e1 * hr[64 + lane];
        acc2 += e2 * hr[128 + lane];
        acc3 += e3 * hr[192 + lane];
        ss0 += e0;
        ss1 += e1;
        ss2 += e2;
        ss3 += e3;
    }
    size_t o = (size_t)n * HC0;
    out[o + lane] = acc0 / (ss0 + 1e-16f) + bias[lane];
    out[o + 64 + lane] = acc1 / (ss1 + 1e-16f) + bias[64 + lane];
    out[o + 128 + lane] = acc2 / (ss2 + 1e-16f) + bias[128 + lane];
    out[o + 192 + lane] = acc3 / (ss3 + 1e-16f) + bias[192 + lane];
}

__global__ __launch_bounds__(256) void k_agg1(
    const float* __restrict__ h1, const float* __restrict__ s_src,
    const float* __restrict__ s_dst, const float* __restrict__ ae1, const float* __restrict__ l1,
    const int* __restrict__ rowptr, const int* __restrict__ eidx, const int* __restrict__ esrc,
    const float* __restrict__ bias, float* __restrict__ out) {
    int gid = blockIdx.x * blockDim.x + threadIdx.x;
    int n = gid >> 6, lane = threadIdx.x & 63;
    if (n >= N_NODES) return;
    int head = lane >> 4;
    float sdv = s_dst[n * 4 + head];
    float lav = l1[head];
    float acc = 0.f, ss = 0.f;
    int p1 = rowptr[n + 1];
    for (int p = rowptr[n]; p < p1; ++p) {
        int t = eidx[p], s = esrc[p];
        float asv = s_src[(size_t)s * 4 + head];
        float aev = (t < N_EDGES) ? ae1[(size_t)t * 4 + head] : lav;
        float a = asv + sdv + aev;
        a = a >= 0.f ? a : SLOPE * a;
        float e = expf(a);
        acc += e * h1[(size_t)s * HC1 + lane];
        ss += e;
    }
    out[(size_t)n * HC1 + lane] = acc / (ss + 1e-16f) + bias[lane];
}

// ---------------------------------------------------------------------------
extern "C" void kernel_launch(void* const* d_in, const int* in_sizes, int n_in, void* d_out,
                              int out_size, void* d_ws, size_t ws_size, hipStream_t stream) {
    const float* x = (const float*)d_in[0];
    const int* ei = (const int*)d_in[1];
    const float* ts = (const float*)d_in[2];
    const float* time_w = (const float*)d_in[3];
    const float* time_b = (const float*)d_in[4];
    const float* W0 = (const float*)d_in[5];
    const float* att_src0 = (const float*)d_in[6];
    const float* att_dst0 = (const float*)d_in[7];
    const float* lin_edge0 = (const float*)d_in[8];
    const float* att_edge0 = (const float*)d_in[9];
    const float* bias0 = (const float*)d_in[10];
    const float* W1 = (const float*)d_in[11];
    const float* att_src1 = (const float*)d_in[12];
    const float* att_dst1 = (const float*)d_in[13];
    const float* lin_edge1 = (const float*)d_in[14];
    const float* att_edge1 = (const float*)d_in[15];
    const float* bias1 = (const float*)d_in[16];
    float* out = (float*)d_out;

    char* ws = (char*)d_ws;
    size_t off = 0;
    auto alloc = [&](size_t bytes) -> void* {
        void* p = ws + off;
        off = (off + bytes + 255) & ~(size_t)255;
        return p;
    };
    float* h0 = (float*)alloc((size_t)N_NODES * HC0 * 4);    // reused as h1 after agg0
    float* out0 = (float*)alloc((size_t)N_NODES * HC0 * 4);
    float* ae0 = (float*)alloc((size_t)N_EDGES * 4 * 4);
    float* ae1 = (float*)alloc((size_t)N_EDGES * 4 * 4);
    float* ssrc0 = (float*)alloc((size_t)N_NODES * 4 * 4);
    float* sdst0 = (float*)alloc((size_t)N_NODES * 4 * 4);
    float* ssrc1 = (float*)alloc((size_t)N_NODES * 4 * 4);
    float* sdst1 = (float*)alloc((size_t)N_NODES * 4 * 4);
    float* v0 = (float*)alloc(TDIM * 4 * 4);
    float* v1 = (float*)alloc(TDIM * 4 * 4);
    float* l0 = (float*)alloc(16);
    float* l1 = (float*)alloc(16);
    int* deg = (int*)alloc((size_t)N_NODES * 4);
    int* rowptr = (int*)alloc((size_t)(N_NODES + 1) * 4);
    int* cursor = (int*)alloc((size_t)N_NODES * 4);
    int* blocksum = (int*)alloc(256 * 4);
    int* blockoff = (int*)alloc(256 * 4);
    int* eidx = (int*)alloc((size_t)ET * 4);
    int* esrc = (int*)alloc((size_t)ET * 4);
    float* h1 = h0;
    (void)ws_size;
    (void)in_sizes;
    (void)n_in;
    (void)out_size;

    int nb = (N_NODES + 255) / 256;  // 196

    k_tables<<<1, 256, 0, stream>>>(lin_edge0, att_edge0, lin_edge1, att_edge1, v0, v1, l0, l1);
    k_timeenc<<<(N_EDGES + 255) / 256, 256, 0, stream>>>(ts, time_w, time_b, v0, v1, ae0, ae1);

    k_zero<<<nb, 256, 0, stream>>>(deg, N_NODES);
    k_count<<<(ET + 255) / 256, 256, 0, stream>>>(ei, deg);
    k_scan_block<<<nb, 256, 0, stream>>>(deg, rowptr, blocksum, N_NODES);
    k_scan_top<<<1, 256, 0, stream>>>(blocksum, blockoff, nb);
    k_scan_add<<<nb, 256, 0, stream>>>(rowptr, blockoff, N_NODES);
    k_cursor<<<nb, 256, 0, stream>>>(rowptr, cursor, N_NODES);
    k_scatter<<<(ET + 255) / 256, 256, 0, stream>>>(ei, cursor, eidx, esrc);

    // Layer 0
    k_gemm<<<dim3(HC0 / 64, (N_NODES + 127) / 128), 256, 0, stream>>>(x, W0, h0, N_NODES, IN_F,
                                                                      HC0);
    k_scores0<<<(N_NODES * 64 + 255) / 256, 256, 0, stream>>>(h0, att_src0, att_dst0, ssrc0, sdst0);
    k_agg0<<<(N_NODES * 64 + 255) / 256, 256, 0, stream>>>(h0, ssrc0, sdst0, ae0, l0, rowptr, eidx,
                                                           esrc, bias0, out0);

    // Layer 1
    k_gemm<<<dim3(HC1 / 64, (N_NODES + 127) / 128), 256, 0, stream>>>(out0, W1, h1, N_NODES, HC0,
                                                                      HC1);
    k_scores1<<<(N_NODES * 64 + 255) / 256, 256, 0, stream>>>(h1, att_src1, att_dst1, ssrc1, sdst1);
    k_agg1<<<(N_NODES * 64 + 255) / 256, 256, 0, stream>>>(h1, ssrc1, sdst1, ae1, l1, rowptr, eidx,
                                                           esrc, bias1, out);
}

// Round 2
// 498.899 us; speedup vs baseline: 1.0432x; 1.0432x over previous
//
#include <hip/hip_runtime.h>
#include <math.h>

#define N_NODES 50000
#define N_EDGES 800000
#define ET (N_EDGES + N_NODES)
#define IN_F 128
#define TDIM 64
#define HEADS 4
#define C0 64
#define C1 16
#define HC0 (HEADS * C0) /* 256 */
#define HC1 (HEADS * C1) /* 64  */
#define SLOPE 0.2f

using short8 = __attribute__((ext_vector_type(8))) short;
using f32x4 = __attribute__((ext_vector_type(4))) float;

__device__ __forceinline__ float bf2f(unsigned u16) {
    return __uint_as_float(u16 << 16);
}
__device__ __forceinline__ unsigned short f2bf(float f) {
    unsigned u = __float_as_uint(f);
    return (unsigned short)((u + 0x7fffu + ((u >> 16) & 1u)) >> 16);
}
__device__ __forceinline__ unsigned pk2(float lo, float hi) {
    return (unsigned)f2bf(lo) | ((unsigned)f2bf(hi) << 16);
}

// ---------------------------------------------------------------------------
// Pre-contract lin_edge with att_edge: v[td][h] = sum_c lin_e[td][h*C+c]*att_e[h][c]
// Also loop_alpha[h] = sum_td v[td][h]  (self-loop edge feature is all-ones)
__global__ void k_tables(const float* __restrict__ lin_e0, const float* __restrict__ att_e0,
                         const float* __restrict__ lin_e1, const float* __restrict__ att_e1,
                         float* __restrict__ v0, float* __restrict__ v1,
                         float* __restrict__ l0, float* __restrict__ l1) {
    int tid = threadIdx.x;  // 256 threads
    int td = tid >> 2, h = tid & 3;
    float s0 = 0.f;
    for (int c = 0; c < C0; ++c) s0 += lin_e0[td * HC0 + h * C0 + c] * att_e0[h * C0 + c];
    v0[td * 4 + h] = s0;
    float s1 = 0.f;
    for (int c = 0; c < C1; ++c) s1 += lin_e1[td * HC1 + h * C1 + c] * att_e1[h * C1 + c];
    v1[td * 4 + h] = s1;
    __syncthreads();
    if (tid < 4) {
        float a0 = 0.f, a1 = 0.f;
        for (int t = 0; t < TDIM; ++t) {
            a0 += v0[t * 4 + tid];
            a1 += v1[t * 4 + tid];
        }
        l0[tid] = a0;
        l1[tid] = a1;
    }
}

// ---------------------------------------------------------------------------
// Per real edge: ef[td] = |cos(ts*w[td]+b[td])| ; ae[t][h] = sum_td ef[td]*v[td][h]
__global__ void k_timeenc(const float* __restrict__ ts, const float* __restrict__ tw,
                          const float* __restrict__ tb, const float* __restrict__ v0,
                          const float* __restrict__ v1, float* __restrict__ ae0,
                          float* __restrict__ ae1) {
    __shared__ float sw[TDIM], sb[TDIM], sv0[TDIM * 4], sv1[TDIM * 4];
    int tid = threadIdx.x;
    if (tid < TDIM) {
        sw[tid] = tw[tid];
        sb[tid] = tb[tid];
    }
    sv0[tid] = v0[tid];
    sv1[tid] = v1[tid];
    __syncthreads();
    int t = blockIdx.x * blockDim.x + tid;
    if (t >= N_EDGES) return;
    float time = ts[t];
    float a00 = 0, a01 = 0, a02 = 0, a03 = 0, a10 = 0, a11 = 0, a12 = 0, a13 = 0;
#pragma unroll 8
    for (int d = 0; d < TDIM; ++d) {
        float f = fabsf(__cosf(time * sw[d] + sb[d]));
        a00 += f * sv0[d * 4 + 0];
        a01 += f * sv0[d * 4 + 1];
        a02 += f * sv0[d * 4 + 2];
        a03 += f * sv0[d * 4 + 3];
        a10 += f * sv1[d * 4 + 0];
        a11 += f * sv1[d * 4 + 1];
        a12 += f * sv1[d * 4 + 2];
        a13 += f * sv1[d * 4 + 3];
    }
    ((float4*)ae0)[t] = make_float4(a00, a01, a02, a03);
    ((float4*)ae1)[t] = make_float4(a10, a11, a12, a13);
}

// ---------------------------------------------------------------------------
// CSR build over destination node (shared by both layers)
__global__ void k_zero(int* __restrict__ p, int n) {
    int i = blockIdx.x * blockDim.x + threadIdx.x;
    if (i < n) p[i] = 0;
}

__global__ void k_count(const int* __restrict__ ei, int* __restrict__ deg) {
    int t = blockIdx.x * blockDim.x + threadIdx.x;
    if (t >= ET) return;
    int d = (t < N_EDGES) ? ei[N_EDGES + t] : (t - N_EDGES);
    atomicAdd(&deg[d], 1);
}

__global__ void k_scan_block(const int* __restrict__ deg, int* __restrict__ rowptr,
                             int* __restrict__ blocksum, int n) {
    __shared__ int buf[256];
    int tid = threadIdx.x, i = blockIdx.x * 256 + tid;
    int v = (i < n) ? deg[i] : 0;
    buf[tid] = v;
    __syncthreads();
    for (int off = 1; off < 256; off <<= 1) {
        int t = (tid >= off) ? buf[tid - off] : 0;
        __syncthreads();
        buf[tid] += t;
        __syncthreads();
    }
    if (i < n) rowptr[i + 1] = buf[tid];
    if (tid == 255) blocksum[blockIdx.x] = buf[255];
}

__global__ void k_scan_top(const int* __restrict__ blocksum, int* __restrict__ blockoff, int nb) {
    __shared__ int buf[256];
    int tid = threadIdx.x;
    int v = (tid < nb) ? blocksum[tid] : 0;
    buf[tid] = v;
    __syncthreads();
    for (int off = 1; off < 256; off <<= 1) {
        int t = (tid >= off) ? buf[tid - off] : 0;
        __syncthreads();
        buf[tid] += t;
        __syncthreads();
    }
    if (tid < nb) blockoff[tid] = buf[tid] - v;  // exclusive
}

__global__ void k_scan_add(int* __restrict__ rowptr, const int* __restrict__ blockoff, int n) {
    int i = blockIdx.x * 256 + threadIdx.x;
    if (i < n) rowptr[i + 1] += blockoff[blockIdx.x];
    if (i == 0) rowptr[0] = 0;
}

__global__ void k_cursor(const int* __restrict__ rowptr, int* __restrict__ cursor, int n) {
    int i = blockIdx.x * 256 + threadIdx.x;
    if (i < n) cursor[i] = rowptr[i];
}

__global__ void k_scatter(const int* __restrict__ ei, int* __restrict__ cursor,
                          int2* __restrict__ epack) {
    int t = blockIdx.x * blockDim.x + threadIdx.x;
    if (t >= ET) return;
    int d, s;
    if (t < N_EDGES) {
        s = ei[t];
        d = ei[N_EDGES + t];
    } else {
        s = t - N_EDGES;
        d = t - N_EDGES;
    }
    int p = atomicAdd(&cursor[d], 1);
    epack[p] = make_int2(t, s);
}

// ---------------------------------------------------------------------------
// Weight transpose + bf16: Wt[n][k] = bf16(W[k][n])
__global__ void k_wt(const float* __restrict__ W, unsigned short* __restrict__ Wt, int K, int Nc) {
    int n = blockIdx.x * blockDim.x + threadIdx.x;
    if (n >= Nc) return;
    for (int k = 0; k < K; ++k) Wt[(size_t)n * K + k] = f2bf(W[(size_t)k * Nc + n]);
}

// ---------------------------------------------------------------------------
// MFMA bf16 GEMM: C[M,Nc](bf16) = A[M,K] @ Bt[Nc,K]^T, A f32 (converted inline) or bf16.
// Tile 128x64, 4 waves (each 32 rows x 64 cols), BK=32, 16x16x32 mfma.
template <bool AF32>
__global__ __launch_bounds__(256) void k_gemm_mfma(const void* __restrict__ Av,
                                                   const unsigned short* __restrict__ Bt,
                                                   unsigned short* __restrict__ C, int M, int K,
                                                   int Nc) {
    __shared__ unsigned short As[128 * 40];  // stride 40 shorts (=80B) breaks bank conflicts
    __shared__ unsigned short Bs[64 * 40];
    int tid = threadIdx.x;
    int w = tid >> 6, l = tid & 63;
    int m0 = blockIdx.y * 128, n0 = blockIdx.x * 64;
    f32x4 acc[2][4];
#pragma unroll
    for (int i = 0; i < 2; ++i)
#pragma unroll
        for (int j = 0; j < 4; ++j) acc[i][j] = (f32x4){0.f, 0.f, 0.f, 0.f};

    int arow = tid >> 1, aseg = tid & 1;  // A stage: 128 rows x 2 x (16 bf16)
    int brow = tid >> 2, bseg = tid & 3;  // B stage: 64 rows x 4 x (8 bf16)

    for (int k0 = 0; k0 < K; k0 += 32) {
        uint4 w0 = {0, 0, 0, 0}, w1 = {0, 0, 0, 0};
        bool av = (m0 + arow) < M;
        if (AF32) {
            if (av) {
                const float* p = (const float*)Av + (size_t)(m0 + arow) * K + k0 + aseg * 16;
                float4 a0 = ((const float4*)p)[0];
                float4 a1 = ((const float4*)p)[1];
                float4 a2 = ((const float4*)p)[2];
                float4 a3 = ((const float4*)p)[3];
                w0.x = pk2(a0.x, a0.y);
                w0.y = pk2(a0.z, a0.w);
                w0.z = pk2(a1.x, a1.y);
                w0.w = pk2(a1.z, a1.w);
                w1.x = pk2(a2.x, a2.y);
                w1.y = pk2(a2.z, a2.w);
                w1.z = pk2(a3.x, a3.y);
                w1.w = pk2(a3.z, a3.w);
            }
        } else {
            if (av) {
                const uint4* p =
                    (const uint4*)((const unsigned short*)Av + (size_t)(m0 + arow) * K + k0 +
                                   aseg * 16);
                w0 = p[0];
                w1 = p[1];
            }
        }
        *(uint4*)&As[arow * 40 + aseg * 16] = w0;
        *(uint4*)&As[arow * 40 + aseg * 16 + 8] = w1;
        uint4 wb = *(const uint4*)(Bt + (size_t)(n0 + brow) * K + k0 + bseg * 8);
        *(uint4*)&Bs[brow * 40 + bseg * 8] = wb;
        __syncthreads();

        short8 af[2], bf[4];
#pragma unroll
        for (int fa = 0; fa < 2; ++fa)
            af[fa] = *(const short8*)&As[(w * 32 + fa * 16 + (l & 15)) * 40 + (l >> 4) * 8];
#pragma unroll
        for (int nf = 0; nf < 4; ++nf)
            bf[nf] = *(const short8*)&Bs[(nf * 16 + (l & 15)) * 40 + (l >> 4) * 8];
#pragma unroll
        for (int fa = 0; fa < 2; ++fa)
#pragma unroll
            for (int nf = 0; nf < 4; ++nf)
                acc[fa][nf] =
                    __builtin_amdgcn_mfma_f32_16x16x32_bf16(af[fa], bf[nf], acc[fa][nf], 0, 0, 0);
        __syncthreads();
    }
// epilogue: C/D layout col=lane&15, row=(lane>>4)*4+reg
#pragma unroll
    for (int fa = 0; fa < 2; ++fa)
#pragma unroll
        for (int nf = 0; nf < 4; ++nf) {
            int col = n0 + nf * 16 + (l & 15);
#pragma unroll
            for (int r = 0; r < 4; ++r) {
                int row = m0 + w * 32 + fa * 16 + (l >> 4) * 4 + r;
                if (row < M) C[(size_t)row * Nc + col] = f2bf(acc[fa][nf][r]);
            }
        }
}

// ---------------------------------------------------------------------------
// Per-node score dots from bf16 h: lane owns 4 channels (layer0) / 1 channel (layer1)
__global__ void k_scores0(const unsigned short* __restrict__ h0b, const float* __restrict__ a_src,
                          const float* __restrict__ a_dst, float* __restrict__ s_src,
                          float* __restrict__ s_dst) {
    int gid = blockIdx.x * blockDim.x + threadIdx.x;
    int n = gid >> 6, l = threadIdx.x & 63;
    if (n >= N_NODES) return;
    uint2 hv = *(const uint2*)(h0b + (size_t)n * HC0 + l * 4);
    float f0 = bf2f(hv.x & 0xffff), f1 = bf2f(hv.x >> 16);
    float f2 = bf2f(hv.y & 0xffff), f3 = bf2f(hv.y >> 16);
    float4 as = *(const float4*)(a_src + l * 4);
    float4 ad = *(const float4*)(a_dst + l * 4);
    float ps = f0 * as.x + f1 * as.y + f2 * as.z + f3 * as.w;
    float pd = f0 * ad.x + f1 * ad.y + f2 * ad.z + f3 * ad.w;
    for (int m = 1; m < 16; m <<= 1) {
        ps += __shfl_xor(ps, m);
        pd += __shfl_xor(pd, m);
    }
    if ((l & 15) == 0) {
        s_src[n * 4 + (l >> 4)] = ps;
        s_dst[n * 4 + (l >> 4)] = pd;
    }
}

__global__ void k_scores1(const unsigned short* __restrict__ h1b, const float* __restrict__ a_src,
                          const float* __restrict__ a_dst, float* __restrict__ s_src,
                          float* __restrict__ s_dst) {
    int gid = blockIdx.x * blockDim.x + threadIdx.x;
    int n = gid >> 6, l = threadIdx.x & 63;
    if (n >= N_NODES) return;
    float f = bf2f(h1b[(size_t)n * HC1 + l]);
    float ps = f * a_src[l];
    float pd = f * a_dst[l];
    for (int m = 1; m < 16; m <<= 1) {
        ps += __shfl_xor(ps, m);
        pd += __shfl_xor(pd, m);
    }
    if ((l & 15) == 0) {
        s_src[n * 4 + (l >> 4)] = ps;
        s_dst[n * 4 + (l >> 4)] = pd;
    }
}

// ---------------------------------------------------------------------------
// Fused softmax + aggregation, one wave per dst node. Lane owns 4 channels of
// one head; computes only its own head's exp. h gathered as bf16 (8B/lane/edge).
__global__ __launch_bounds__(256) void k_agg0(
    const unsigned short* __restrict__ h0b, const float* __restrict__ s_src,
    const float* __restrict__ s_dst, const float* __restrict__ ae0, const float* __restrict__ l0,
    const int* __restrict__ rowptr, const int2* __restrict__ epack,
    const float* __restrict__ bias, unsigned short* __restrict__ out0b) {
    int gid = blockIdx.x * blockDim.x + threadIdx.x;
    int n = gid >> 6, l = threadIdx.x & 63;
    if (n >= N_NODES) return;
    int head = l >> 4;
    float sdv = s_dst[n * 4 + head];
    float lav = l0[head];
    float a0 = 0, a1 = 0, a2 = 0, a3 = 0, ss = 0;
    int p1 = rowptr[n + 1];
    for (int p = rowptr[n]; p < p1; ++p) {
        int2 es = epack[p];
        int t = es.x, s = es.y;
        float asv = s_src[s * 4 + head];
        float aev = (t < N_EDGES) ? ae0[(size_t)t * 4 + head] : lav;
        float a = asv + sdv + aev;
        a = a >= 0.f ? a : SLOPE * a;
        float e = __expf(a);
        uint2 hv = *(const uint2*)(h0b + (size_t)s * HC0 + l * 4);
        a0 += e * bf2f(hv.x & 0xffff);
        a1 += e * bf2f(hv.x >> 16);
        a2 += e * bf2f(hv.y & 0xffff);
        a3 += e * bf2f(hv.y >> 16);
        ss += e;
    }
    float inv = 1.f / (ss + 1e-16f);
    float4 b4 = *(const float4*)(bias + l * 4);
    unsigned r0 = pk2(a0 * inv + b4.x, a1 * inv + b4.y);
    unsigned r1 = pk2(a2 * inv + b4.z, a3 * inv + b4.w);
    *(uint2*)(out0b + (size_t)n * HC0 + l * 4) = make_uint2(r0, r1);
}

__global__ __launch_bounds__(256) void k_agg1(
    const unsigned short* __restrict__ h1b, const float* __restrict__ s_src,
    const float* __restrict__ s_dst, const float* __restrict__ ae1, const float* __restrict__ l1,
    const int* __restrict__ rowptr, const int2* __restrict__ epack,
    const float* __restrict__ bias, float* __restrict__ out) {
    int gid = blockIdx.x * blockDim.x + threadIdx.x;
    int n = gid >> 6, l = threadIdx.x & 63;
    if (n >= N_NODES) return;
    int head = l >> 4;
    float sdv = s_dst[n * 4 + head];
    float lav = l1[head];
    float acc = 0.f, ss = 0.f;
    int p1 = rowptr[n + 1];
    for (int p = rowptr[n]; p < p1; ++p) {
        int2 es = epack[p];
        int t = es.x, s = es.y;
        float asv = s_src[s * 4 + head];
        float aev = (t < N_EDGES) ? ae1[(size_t)t * 4 + head] : lav;
        float a = asv + sdv + aev;
        a = a >= 0.f ? a : SLOPE * a;
        float e = __expf(a);
        acc += e * bf2f(h1b[(size_t)s * HC1 + l]);
        ss += e;
    }
    out[(size_t)n * HC1 + l] = acc / (ss + 1e-16f) + bias[l];
}

// ---------------------------------------------------------------------------
extern "C" void kernel_launch(void* const* d_in, const int* in_sizes, int n_in, void* d_out,
                              int out_size, void* d_ws, size_t ws_size, hipStream_t stream) {
    const float* x = (const float*)d_in[0];
    const int* ei = (const int*)d_in[1];
    const float* ts = (const float*)d_in[2];
    const float* time_w = (const float*)d_in[3];
    const float* time_b = (const float*)d_in[4];
    const float* W0 = (const float*)d_in[5];
    const float* att_src0 = (const float*)d_in[6];
    const float* att_dst0 = (const float*)d_in[7];
    const float* lin_edge0 = (const float*)d_in[8];
    const float* att_edge0 = (const float*)d_in[9];
    const float* bias0 = (const float*)d_in[10];
    const float* W1 = (const float*)d_in[11];
    const float* att_src1 = (const float*)d_in[12];
    const float* att_dst1 = (const float*)d_in[13];
    const float* lin_edge1 = (const float*)d_in[14];
    const float* att_edge1 = (const float*)d_in[15];
    const float* bias1 = (const float*)d_in[16];
    float* out = (float*)d_out;

    char* ws = (char*)d_ws;
    size_t off = 0;
    auto alloc = [&](size_t bytes) -> void* {
        void* p = ws + off;
        off = (off + bytes + 255) & ~(size_t)255;
        return p;
    };
    unsigned short* h0b = (unsigned short*)alloc((size_t)N_NODES * HC0 * 2);
    unsigned short* out0b = (unsigned short*)alloc((size_t)N_NODES * HC0 * 2);
    unsigned short* h1b = (unsigned short*)alloc((size_t)N_NODES * HC1 * 2);
    unsigned short* Wt0 = (unsigned short*)alloc((size_t)IN_F * HC0 * 2);
    unsigned short* Wt1 = (unsigned short*)alloc((size_t)HC0 * HC1 * 2);
    float* ae0 = (float*)alloc((size_t)N_EDGES * 4 * 4);
    float* ae1 = (float*)alloc((size_t)N_EDGES * 4 * 4);
    float* ssrc0 = (float*)alloc((size_t)N_NODES * 4 * 4);
    float* sdst0 = (float*)alloc((size_t)N_NODES * 4 * 4);
    float* ssrc1 = (float*)alloc((size_t)N_NODES * 4 * 4);
    float* sdst1 = (float*)alloc((size_t)N_NODES * 4 * 4);
    float* v0 = (float*)alloc(TDIM * 4 * 4);
    float* v1 = (float*)alloc(TDIM * 4 * 4);
    float* l0 = (float*)alloc(16);
    float* l1 = (float*)alloc(16);
    int* deg = (int*)alloc((size_t)N_NODES * 4);
    int* rowptr = (int*)alloc((size_t)(N_NODES + 1) * 4);
    int* cursor = (int*)alloc((size_t)N_NODES * 4);
    int* blocksum = (int*)alloc(256 * 4);
    int* blockoff = (int*)alloc(256 * 4);
    int2* epack = (int2*)alloc((size_t)ET * 8);
    (void)ws_size;
    (void)in_sizes;
    (void)n_in;
    (void)out_size;

    int nb = (N_NODES + 255) / 256;  // 196

    k_tables<<<1, 256, 0, stream>>>(lin_edge0, att_edge0, lin_edge1, att_edge1, v0, v1, l0, l1);
    k_timeenc<<<(N_EDGES + 255) / 256, 256, 0, stream>>>(ts, time_w, time_b, v0, v1, ae0, ae1);

    k_zero<<<nb, 256, 0, stream>>>(deg, N_NODES);
    k_count<<<(ET + 255) / 256, 256, 0, stream>>>(ei, deg);
    k_scan_block<<<nb, 256, 0, stream>>>(deg, rowptr, blocksum, N_NODES);
    k_scan_top<<<1, 256, 0, stream>>>(blocksum, blockoff, nb);
    k_scan_add<<<nb, 256, 0, stream>>>(rowptr, blockoff, N_NODES);
    k_cursor<<<nb, 256, 0, stream>>>(rowptr, cursor, N_NODES);
    k_scatter<<<(ET + 255) / 256, 256, 0, stream>>>(ei, cursor, epack);

    k_wt<<<1, 256, 0, stream>>>(W0, Wt0, IN_F, HC0);
    k_wt<<<1, 256, 0, stream>>>(W1, Wt1, HC0, HC1);

    // Layer 0
    k_gemm_mfma<true><<<dim3(HC0 / 64, (N_NODES + 127) / 128), 256, 0, stream>>>(
        x, Wt0, h0b, N_NODES, IN_F, HC0);
    k_scores0<<<(N_NODES * 64 + 255) / 256, 256, 0, stream>>>(h0b, att_src0, att_dst0, ssrc0,
                                                              sdst0);
    k_agg0<<<(N_NODES * 64 + 255) / 256, 256, 0, stream>>>(h0b, ssrc0, sdst0, ae0, l0, rowptr,
                                                           epack, bias0, out0b);

    // Layer 1
    k_gemm_mfma<false><<<dim3(HC1 / 64, (N_NODES + 127) / 128), 256, 0, stream>>>(
        out0b, Wt1, h1b, N_NODES, HC0, HC1);
    k_scores1<<<(N_NODES * 64 + 255) / 256, 256, 0, stream>>>(h1b, att_src1, att_dst1, ssrc1,
                                                              sdst1);
    k_agg1<<<(N_NODES * 64 + 255) / 256, 256, 0, stream>>>(h1b, ssrc1, sdst1, ae1, l1, rowptr,
                                                           epack, bias1, out);
}

// Round 3
// 393.017 us; speedup vs baseline: 1.3242x; 1.2694x over previous
//
#include <hip/hip_runtime.h>
#include <math.h>

#define N_NODES 50000
#define N_EDGES 800000
#define ET (N_EDGES + N_NODES)
#define IN_F 128
#define TDIM 64
#define HEADS 4
#define C0 64
#define C1 16
#define HC0 256
#define HC1 64
#define SLOPE 0.2f

using short8 = __attribute__((ext_vector_type(8))) short;
using f32x4 = __attribute__((ext_vector_type(4))) float;

__device__ __forceinline__ float bf2f(unsigned u16) { return __uint_as_float(u16 << 16); }
__device__ __forceinline__ unsigned short f2bf(float f) {
    unsigned u = __float_as_uint(f);
    return (unsigned short)((u + 0x7fffu + ((u >> 16) & 1u)) >> 16);
}
__device__ __forceinline__ unsigned pk2(float lo, float hi) {
    return (unsigned)f2bf(lo) | ((unsigned)f2bf(hi) << 16);
}

// ---------------------------------------------------------------------------
// v[td][h] = sum_c lin_e[td][h*C+c] * att_e[h][c]   (one block per td)
__global__ void k_tables(const float* __restrict__ le0, const float* __restrict__ at0,
                         const float* __restrict__ le1, const float* __restrict__ at1,
                         float* __restrict__ v0, float* __restrict__ v1) {
    int td = blockIdx.x;
    int tid = threadIdx.x;  // 256
    int h = tid >> 6, c = tid & 63;
    float p0 = le0[td * HC0 + h * C0 + c] * at0[h * C0 + c];
    for (int m = 1; m < 64; m <<= 1) p0 += __shfl_xor(p0, m);
    if (c == 0) v0[td * 4 + h] = p0;
    float p1 = 0.f;
    if (c < C1) p1 = le1[td * HC1 + h * C1 + c] * at1[h * C1 + c];
    for (int m = 1; m < 16; m <<= 1) p1 += __shfl_xor(p1, m);
    if (c == 0) v1[td * 4 + h] = p1;
}

// l[h] = sum_td v[td][h]  (self-loop logit; edge feature all-ones)
__global__ void k_l(const float* __restrict__ v0, const float* __restrict__ v1,
                    float* __restrict__ l0, float* __restrict__ l1) {
    int tid = threadIdx.x;  // 128
    int w = tid >> 6, l = tid & 63;
    const float4* v = (const float4*)(w ? v1 : v0);
    float4 a = v[l];
    for (int m = 1; m < 64; m <<= 1) {
        a.x += __shfl_xor(a.x, m);
        a.y += __shfl_xor(a.y, m);
        a.z += __shfl_xor(a.z, m);
        a.w += __shfl_xor(a.w, m);
    }
    if (l == 0) ((float4*)(w ? l1 : l0))[0] = a;
}

// x -> bf16
__global__ void k_xb(const float* __restrict__ x, unsigned short* __restrict__ xb) {
    int i = blockIdx.x * blockDim.x + threadIdx.x;
    if (i >= N_NODES * IN_F / 8) return;
    const float4* p = (const float4*)(x + (size_t)i * 8);
    float4 a = p[0], b = p[1];
    uint4 r = {pk2(a.x, a.y), pk2(a.z, a.w), pk2(b.x, b.y), pk2(b.z, b.w)};
    ((uint4*)xb)[i] = r;
}

// ---------------------------------------------------------------------------
// Per real edge: ef[td]=|cos(ts*w+b)|; ae[t][h] = sum_td ef[td]*v[td][h]
__global__ void k_timeenc(const float* __restrict__ ts, const float* __restrict__ tw,
                          const float* __restrict__ tb, const float* __restrict__ v0,
                          const float* __restrict__ v1, float* __restrict__ ae0,
                          float* __restrict__ ae1) {
    __shared__ float sw[TDIM], sb[TDIM], sv0[TDIM * 4], sv1[TDIM * 4];
    int tid = threadIdx.x;
    if (tid < TDIM) {
        sw[tid] = tw[tid];
        sb[tid] = tb[tid];
    }
    sv0[tid] = v0[tid];
    sv1[tid] = v1[tid];
    __syncthreads();
    int t = blockIdx.x * blockDim.x + tid;
    if (t >= N_EDGES) return;
    float time = ts[t];
    float a00 = 0, a01 = 0, a02 = 0, a03 = 0, a10 = 0, a11 = 0, a12 = 0, a13 = 0;
#pragma unroll 8
    for (int d = 0; d < TDIM; ++d) {
        float f = fabsf(__cosf(time * sw[d] + sb[d]));
        a00 += f * sv0[d * 4 + 0];
        a01 += f * sv0[d * 4 + 1];
        a02 += f * sv0[d * 4 + 2];
        a03 += f * sv0[d * 4 + 3];
        a10 += f * sv1[d * 4 + 0];
        a11 += f * sv1[d * 4 + 1];
        a12 += f * sv1[d * 4 + 2];
        a13 += f * sv1[d * 4 + 3];
    }
    ((float4*)ae0)[t] = make_float4(a00, a01, a02, a03);
    ((float4*)ae1)[t] = make_float4(a10, a11, a12, a13);
}

// ---------------------------------------------------------------------------
// CSR build over destination node (shared by both layers)
__global__ void k_zero(int* __restrict__ p, int n) {
    int i = blockIdx.x * blockDim.x + threadIdx.x;
    if (i < n) p[i] = 0;
}

__global__ void k_count(const int* __restrict__ ei, int* __restrict__ deg) {
    int t = blockIdx.x * blockDim.x + threadIdx.x;
    if (t >= ET) return;
    int d = (t < N_EDGES) ? ei[N_EDGES + t] : (t - N_EDGES);
    atomicAdd(&deg[d], 1);
}

__global__ void k_scan_block(const int* __restrict__ deg, int* __restrict__ rowptr,
                             int* __restrict__ blocksum, int n) {
    __shared__ int buf[256];
    int tid = threadIdx.x, i = blockIdx.x * 256 + tid;
    int v = (i < n) ? deg[i] : 0;
    buf[tid] = v;
    __syncthreads();
    for (int off = 1; off < 256; off <<= 1) {
        int t = (tid >= off) ? buf[tid - off] : 0;
        __syncthreads();
        buf[tid] += t;
        __syncthreads();
    }
    if (i < n) rowptr[i + 1] = buf[tid];
    if (tid == 255) blocksum[blockIdx.x] = buf[255];
}

__global__ void k_scan_top(const int* __restrict__ blocksum, int* __restrict__ blockoff, int nb) {
    __shared__ int buf[256];
    int tid = threadIdx.x;
    int v = (tid < nb) ? blocksum[tid] : 0;
    buf[tid] = v;
    __syncthreads();
    for (int off = 1; off < 256; off <<= 1) {
        int t = (tid >= off) ? buf[tid - off] : 0;
        __syncthreads();
        buf[tid] += t;
        __syncthreads();
    }
    if (tid < nb) blockoff[tid] = buf[tid] - v;  // exclusive
}

__global__ void k_scan_add(int* __restrict__ rowptr, const int* __restrict__ blockoff,
                           int* __restrict__ cursor, int n) {
    int i = blockIdx.x * 256 + threadIdx.x;
    if (i < n) {
        int v = rowptr[i + 1] + blockoff[blockIdx.x];
        rowptr[i + 1] = v;
        cursor[i + 1] = v;
    }
    if (i == 0) {
        rowptr[0] = 0;
        cursor[0] = 0;
    }
}

__global__ void k_scatter(const int* __restrict__ ei, int* __restrict__ cursor,
                          int* __restrict__ esrc, int2* __restrict__ emeta) {
    int t = blockIdx.x * blockDim.x + threadIdx.x;
    if (t >= ET) return;
    int d, s;
    if (t < N_EDGES) {
        s = ei[t];
        d = ei[N_EDGES + t];
    } else {
        s = t - N_EDGES;
        d = t - N_EDGES;
    }
    int p = atomicAdd(&cursor[d], 1);
    esrc[p] = s;
    emeta[p] = make_int2(t, d);
}

// ---------------------------------------------------------------------------
// Weight transpose + bf16: Wt[n][k] = bf16(W[k][n]); one block per n
__global__ void k_wt(const float* __restrict__ W, unsigned short* __restrict__ Wt, int K, int Nc) {
    int n = blockIdx.x;
    for (int k = threadIdx.x; k < K; k += 64) Wt[(size_t)n * K + k] = f2bf(W[(size_t)k * Nc + n]);
}

// ---------------------------------------------------------------------------
// h0 = xb @ W0 computed ONLY for scores (fused epilogue); h0 never written.
// Tile 128 x 256(full), 8 waves of 16 rows each, BK=32.
__global__ __launch_bounds__(512) void k_gemm0s(const unsigned short* __restrict__ xb,
                                                const unsigned short* __restrict__ Wt,
                                                const float* __restrict__ a_src,
                                                const float* __restrict__ a_dst,
                                                float* __restrict__ ssrc,
                                                float* __restrict__ sdst) {
    __shared__ unsigned short As[128 * 40];
    __shared__ unsigned short Bs[256 * 40];
    int tid = threadIdx.x, w = tid >> 6, l = tid & 63, lo = l & 15, hi = l >> 4;
    int m0 = blockIdx.x * 128;
    f32x4 acc[16];
#pragma unroll
    for (int i = 0; i < 16; ++i) acc[i] = (f32x4){0.f, 0.f, 0.f, 0.f};
    int arow = tid >> 2, aseg = tid & 3;
    for (int k0 = 0; k0 < IN_F; k0 += 32) {
        uint4 va = {0, 0, 0, 0};
        if (m0 + arow < N_NODES)
            va = *(const uint4*)(xb + (size_t)(m0 + arow) * IN_F + k0 + aseg * 8);
        *(uint4*)&As[arow * 40 + aseg * 8] = va;
#pragma unroll
        for (int hf = 0; hf < 2; ++hf) {
            int brow = hf * 128 + arow;
            uint4 vb = *(const uint4*)(Wt + (size_t)brow * IN_F + k0 + aseg * 8);
            *(uint4*)&Bs[brow * 40 + aseg * 8] = vb;
        }
        __syncthreads();
        short8 af = *(const short8*)&As[(w * 16 + lo) * 40 + hi * 8];
#pragma unroll
        for (int nf = 0; nf < 16; ++nf) {
            short8 bf = *(const short8*)&Bs[(nf * 16 + lo) * 40 + hi * 8];
            acc[nf] = __builtin_amdgcn_mfma_f32_16x16x32_bf16(af, bf, acc[nf], 0, 0, 0);
        }
        __syncthreads();
    }
    float asv[16], adv[16];
#pragma unroll
    for (int nf = 0; nf < 16; ++nf) {
        asv[nf] = a_src[nf * 16 + lo];
        adv[nf] = a_dst[nf * 16 + lo];
    }
#pragma unroll
    for (int r = 0; r < 4; ++r) {
        int row = m0 + w * 16 + hi * 4 + r;
#pragma unroll
        for (int h = 0; h < 4; ++h) {
            float ps = 0.f, pd = 0.f;
#pragma unroll
            for (int j = 0; j < 4; ++j) {
                int nf = h * 4 + j;
                ps += acc[nf][r] * asv[nf];
                pd += acc[nf][r] * adv[nf];
            }
            for (int m = 1; m < 16; m <<= 1) {
                ps += __shfl_xor(ps, m);
                pd += __shfl_xor(pd, m);
            }
            if (lo == 0 && row < N_NODES) {
                ssrc[row * 4 + h] = ps;
                sdst[row * 4 + h] = pd;
            }
        }
    }
}

// ---------------------------------------------------------------------------
// Edge-parallel attention weights: ew[p][h] = exp(leakyrelu(ssrc[s]+sdst[d]+ae[t]))
__global__ void k_ew(const int* __restrict__ esrc, const int2* __restrict__ emeta,
                     const float* __restrict__ ssrc, const float* __restrict__ sdst,
                     const float* __restrict__ ae, const float* __restrict__ lv,
                     float* __restrict__ ew) {
    int p = blockIdx.x * blockDim.x + threadIdx.x;
    if (p >= ET) return;
    int s = esrc[p];
    int2 md = emeta[p];
    float4 av = (md.x < N_EDGES) ? ((const float4*)ae)[md.x] : ((const float4*)lv)[0];
    float4 sv = ((const float4*)ssrc)[s];
    float4 dv = ((const float4*)sdst)[md.y];
    float a0 = sv.x + dv.x + av.x;
    float a1 = sv.y + dv.y + av.y;
    float a2 = sv.z + dv.z + av.z;
    float a3 = sv.w + dv.w + av.w;
    a0 = a0 >= 0.f ? a0 : SLOPE * a0;
    a1 = a1 >= 0.f ? a1 : SLOPE * a1;
    a2 = a2 >= 0.f ? a2 : SLOPE * a2;
    a3 = a3 >= 0.f ? a3 : SLOPE * a3;
    ((float4*)ew)[p] = make_float4(__expf(a0), __expf(a1), __expf(a2), __expf(a3));
}

// ---------------------------------------------------------------------------
// Layer-0 aggregation over x (reordered): Aggx[n][h][k] = sum_e a[h]*xb[s][k]
// One wave per node; lane owns 2 x-channels; 4 B gather per lane per edge.
__global__ __launch_bounds__(256) void k_aggx(const unsigned short* __restrict__ xb,
                                              const float* __restrict__ ew,
                                              const int* __restrict__ rowptr,
                                              const int* __restrict__ esrc,
                                              unsigned short* __restrict__ aggx) {
    int gid = blockIdx.x * blockDim.x + threadIdx.x;
    int n = gid >> 6, l = threadIdx.x & 63;
    if (n >= N_NODES) return;
    int c0 = l * 2;
    float acc00 = 0, acc01 = 0, acc10 = 0, acc11 = 0;
    float acc20 = 0, acc21 = 0, acc30 = 0, acc31 = 0;
    float s0 = 0, s1 = 0, s2 = 0, s3 = 0;
    int p1 = rowptr[n + 1];
    for (int p = rowptr[n]; p < p1; ++p) {
        int s = esrc[p];
        float4 e = ((const float4*)ew)[p];
        unsigned xv = *(const unsigned*)(xb + (size_t)s * IN_F + c0);
        float f0 = bf2f(xv & 0xffff), f1 = bf2f(xv >> 16);
        acc00 += e.x * f0;
        acc01 += e.x * f1;
        acc10 += e.y * f0;
        acc11 += e.y * f1;
        acc20 += e.z * f0;
        acc21 += e.z * f1;
        acc30 += e.w * f0;
        acc31 += e.w * f1;
        s0 += e.x;
        s1 += e.y;
        s2 += e.z;
        s3 += e.w;
    }
    size_t base = (size_t)n * (4 * IN_F) + c0;
    float i0 = 1.f / (s0 + 1e-16f), i1 = 1.f / (s1 + 1e-16f);
    float i2 = 1.f / (s2 + 1e-16f), i3 = 1.f / (s3 + 1e-16f);
    *(unsigned*)(aggx + base + 0 * IN_F) = pk2(acc00 * i0, acc01 * i0);
    *(unsigned*)(aggx + base + 1 * IN_F) = pk2(acc10 * i1, acc11 * i1);
    *(unsigned*)(aggx + base + 2 * IN_F) = pk2(acc20 * i2, acc21 * i2);
    *(unsigned*)(aggx + base + 3 * IN_F) = pk2(acc30 * i3, acc31 * i3);
}

// ---------------------------------------------------------------------------
// Per-head GEMM: out0b[:, hd*64:+64] = Aggx[:, hd, :] @ W0[:, hd block] + bias
// Tile 128x64, 4 waves of 32 rows, BK=32, K=128. blockIdx.y = head.
__global__ __launch_bounds__(256) void k_gemm0b(const unsigned short* __restrict__ aggx,
                                                const unsigned short* __restrict__ Wt,
                                                const float* __restrict__ bias,
                                                unsigned short* __restrict__ out0b) {
    __shared__ unsigned short As[128 * 40];
    __shared__ unsigned short Bs[64 * 40];
    int tid = threadIdx.x, w = tid >> 6, l = tid & 63, lo = l & 15, hi = l >> 4;
    int m0 = blockIdx.x * 128, hd = blockIdx.y;
    const unsigned short* A = aggx + hd * IN_F;                // row stride 4*IN_F
    const unsigned short* B = Wt + (size_t)(hd * C0) * IN_F;   // 64 rows, stride IN_F
    f32x4 acc[2][4];
#pragma unroll
    for (int i = 0; i < 2; ++i)
#pragma unroll
        for (int j = 0; j < 4; ++j) acc[i][j] = (f32x4){0.f, 0.f, 0.f, 0.f};
    int arow4 = tid >> 2, aseg = tid & 3;
    for (int k0 = 0; k0 < IN_F; k0 += 32) {
#pragma unroll
        for (int hf = 0; hf < 2; ++hf) {
            int arow = hf * 64 + arow4;
            uint4 va = {0, 0, 0, 0};
            if (m0 + arow < N_NODES)
                va = *(const uint4*)(A + (size_t)(m0 + arow) * (4 * IN_F) + k0 + aseg * 8);
            *(uint4*)&As[arow * 40 + aseg * 8] = va;
        }
        uint4 vb = *(const uint4*)(B + (size_t)arow4 * IN_F + k0 + aseg * 8);
        *(uint4*)&Bs[arow4 * 40 + aseg * 8] = vb;
        __syncthreads();
        short8 af[2], bf[4];
#pragma unroll
        for (int fa = 0; fa < 2; ++fa)
            af[fa] = *(const short8*)&As[(w * 32 + fa * 16 + lo) * 40 + hi * 8];
#pragma unroll
        for (int nf = 0; nf < 4; ++nf) bf[nf] = *(const short8*)&Bs[(nf * 16 + lo) * 40 + hi * 8];
#pragma unroll
        for (int fa = 0; fa < 2; ++fa)
#pragma unroll
            for (int nf = 0; nf < 4; ++nf)
                acc[fa][nf] =
                    __builtin_amdgcn_mfma_f32_16x16x32_bf16(af[fa], bf[nf], acc[fa][nf], 0, 0, 0);
        __syncthreads();
    }
#pragma unroll
    for (int fa = 0; fa < 2; ++fa)
#pragma unroll
        for (int nf = 0; nf < 4; ++nf) {
            int col = hd * C0 + nf * 16 + lo;
            float bv = bias[col];
#pragma unroll
            for (int r = 0; r < 4; ++r) {
                int row = m0 + w * 32 + fa * 16 + hi * 4 + r;
                if (row < N_NODES) out0b[(size_t)row * HC0 + col] = f2bf(acc[fa][nf][r] + bv);
            }
        }
}

// ---------------------------------------------------------------------------
// h1 = out0b @ W1 ; writes h1b (bf16) + fused scores1. Tile 128x64, K=256.
__global__ __launch_bounds__(256) void k_gemm1s(
    const unsigned short* __restrict__ A, const unsigned short* __restrict__ Bt,
    const float* __restrict__ a_src, const float* __restrict__ a_dst,
    unsigned short* __restrict__ h1b, float* __restrict__ ssrc, float* __restrict__ sdst) {
    __shared__ unsigned short As[128 * 40];
    __shared__ unsigned short Bs[64 * 40];
    int tid = threadIdx.x, w = tid >> 6, l = tid & 63, lo = l & 15, hi = l >> 4;
    int m0 = blockIdx.x * 128;
    f32x4 acc[2][4];
#pragma unroll
    for (int i = 0; i < 2; ++i)
#pragma unroll
        for (int j = 0; j < 4; ++j) acc[i][j] = (f32x4){0.f, 0.f, 0.f, 0.f};
    int arow4 = tid >> 2, aseg = tid & 3;
    for (int k0 = 0; k0 < HC0; k0 += 32) {
#pragma unroll
        for (int hf = 0; hf < 2; ++hf) {
            int arow = hf * 64 + arow4;
            uint4 va = {0, 0, 0, 0};
            if (m0 + arow < N_NODES)
                va = *(const uint4*)(A + (size_t)(m0 + arow) * HC0 + k0 + aseg * 8);
            *(uint4*)&As[arow * 40 + aseg * 8] = va;
        }
        uint4 vb = *(const uint4*)(Bt + (size_t)arow4 * HC0 + k0 + aseg * 8);
        *(uint4*)&Bs[arow4 * 40 + aseg * 8] = vb;
        __syncthreads();
        short8 af[2], bf[4];
#pragma unroll
        for (int fa = 0; fa < 2; ++fa)
            af[fa] = *(const short8*)&As[(w * 32 + fa * 16 + lo) * 40 + hi * 8];
#pragma unroll
        for (int nf = 0; nf < 4; ++nf) bf[nf] = *(const short8*)&Bs[(nf * 16 + lo) * 40 + hi * 8];
#pragma unroll
        for (int fa = 0; fa < 2; ++fa)
#pragma unroll
            for (int nf = 0; nf < 4; ++nf)
                acc[fa][nf] =
                    __builtin_amdgcn_mfma_f32_16x16x32_bf16(af[fa], bf[nf], acc[fa][nf], 0, 0, 0);
        __syncthreads();
    }
    float asv[4], adv[4];
#pragma unroll
    for (int nf = 0; nf < 4; ++nf) {
        asv[nf] = a_src[nf * 16 + lo];
        adv[nf] = a_dst[nf * 16 + lo];
    }
#pragma unroll
    for (int fa = 0; fa < 2; ++fa)
#pragma unroll
        for (int r = 0; r < 4; ++r) {
            int row = m0 + w * 32 + fa * 16 + hi * 4 + r;
#pragma unroll
            for (int nf = 0; nf < 4; ++nf) {
                float v = acc[fa][nf][r];
                if (row < N_NODES) h1b[(size_t)row * HC1 + nf * 16 + lo] = f2bf(v);
                float ps = v * asv[nf], pd = v * adv[nf];
                for (int m = 1; m < 16; m <<= 1) {
                    ps += __shfl_xor(ps, m);
                    pd += __shfl_xor(pd, m);
                }
                if (lo == 0 && row < N_NODES) {
                    ssrc[row * 4 + nf] = ps;
                    sdst[row * 4 + nf] = pd;
                }
            }
        }
}

// ---------------------------------------------------------------------------
// Layer-1 aggregation: gather h1b rows (128 B), one wave per node, lane = channel.
__global__ __launch_bounds__(256) void k_agg1(const unsigned short* __restrict__ h1b,
                                              const float* __restrict__ ew,
                                              const int* __restrict__ rowptr,
                                              const int* __restrict__ esrc,
                                              const float* __restrict__ bias,
                                              float* __restrict__ out) {
    int gid = blockIdx.x * blockDim.x + threadIdx.x;
    int n = gid >> 6, l = threadIdx.x & 63;
    if (n >= N_NODES) return;
    int head = l >> 4;
    float acc = 0.f, ss = 0.f;
    int p1 = rowptr[n + 1];
    for (int p = rowptr[n]; p < p1; ++p) {
        int s = esrc[p];
        float e = ew[p * 4 + head];
        float hv = bf2f(h1b[(size_t)s * HC1 + l]);
        acc += e * hv;
        ss += e;
    }
    out[(size_t)n * HC1 + l] = acc / (ss + 1e-16f) + bias[l];
}

// ---------------------------------------------------------------------------
extern "C" void kernel_launch(void* const* d_in, const int* in_sizes, int n_in, void* d_out,
                              int out_size, void* d_ws, size_t ws_size, hipStream_t stream) {
    const float* x = (const float*)d_in[0];
    const int* ei = (const int*)d_in[1];
    const float* ts = (const float*)d_in[2];
    const float* time_w = (const float*)d_in[3];
    const float* time_b = (const float*)d_in[4];
    const float* W0 = (const float*)d_in[5];
    const float* att_src0 = (const float*)d_in[6];
    const float* att_dst0 = (const float*)d_in[7];
    const float* lin_edge0 = (const float*)d_in[8];
    const float* att_edge0 = (const float*)d_in[9];
    const float* bias0 = (const float*)d_in[10];
    const float* W1 = (const float*)d_in[11];
    const float* att_src1 = (const float*)d_in[12];
    const float* att_dst1 = (const float*)d_in[13];
    const float* lin_edge1 = (const float*)d_in[14];
    const float* att_edge1 = (const float*)d_in[15];
    const float* bias1 = (const float*)d_in[16];
    float* out = (float*)d_out;

    char* ws = (char*)d_ws;
    size_t off = 0;
    auto alloc = [&](size_t bytes) -> void* {
        void* p = ws + off;
        off = (off + bytes + 255) & ~(size_t)255;
        return p;
    };
    unsigned short* xb = (unsigned short*)alloc((size_t)N_NODES * IN_F * 2);
    unsigned short* aggx = (unsigned short*)alloc((size_t)N_NODES * 4 * IN_F * 2);
    unsigned short* out0b = (unsigned short*)alloc((size_t)N_NODES * HC0 * 2);
    unsigned short* h1b = (unsigned short*)alloc((size_t)N_NODES * HC1 * 2);
    unsigned short* Wt0 = (unsigned short*)alloc((size_t)IN_F * HC0 * 2);
    unsigned short* Wt1 = (unsigned short*)alloc((size_t)HC0 * HC1 * 2);
    float* ae0 = (float*)alloc((size_t)N_EDGES * 4 * 4);
    float* ae1 = (float*)alloc((size_t)N_EDGES * 4 * 4);
    float* ew0 = (float*)alloc((size_t)ET * 4 * 4);
    float* ew1 = (float*)alloc((size_t)ET * 4 * 4);
    float* ssrc0 = (float*)alloc((size_t)N_NODES * 4 * 4);
    float* sdst0 = (float*)alloc((size_t)N_NODES * 4 * 4);
    float* ssrc1 = (float*)alloc((size_t)N_NODES * 4 * 4);
    float* sdst1 = (float*)alloc((size_t)N_NODES * 4 * 4);
    float* v0 = (float*)alloc(TDIM * 4 * 4);
    float* v1 = (float*)alloc(TDIM * 4 * 4);
    float* l0 = (float*)alloc(16);
    float* l1 = (float*)alloc(16);
    int* deg = (int*)alloc((size_t)N_NODES * 4);
    int* rowptr = (int*)alloc((size_t)(N_NODES + 1) * 4);
    int* cursor = (int*)alloc((size_t)(N_NODES + 1) * 4);
    int* blocksum = (int*)alloc(256 * 4);
    int* blockoff = (int*)alloc(256 * 4);
    int* esrc = (int*)alloc((size_t)ET * 4);
    int2* emeta = (int2*)alloc((size_t)ET * 8);
    (void)ws_size;
    (void)in_sizes;
    (void)n_in;
    (void)out_size;

    int nb = (N_NODES + 255) / 256;        // 196
    int ebks = (ET + 255) / 256;           // 3321
    int gx = (N_NODES + 127) / 128;        // 391
    int nodeblk = (N_NODES * 64) / 256 + 1;

    k_tables<<<TDIM, 256, 0, stream>>>(lin_edge0, att_edge0, lin_edge1, att_edge1, v0, v1);
    k_l<<<1, 128, 0, stream>>>(v0, v1, l0, l1);
    k_xb<<<(N_NODES * IN_F / 8 + 255) / 256, 256, 0, stream>>>(x, xb);
    k_timeenc<<<(N_EDGES + 255) / 256, 256, 0, stream>>>(ts, time_w, time_b, v0, v1, ae0, ae1);

    k_zero<<<nb, 256, 0, stream>>>(deg, N_NODES);
    k_count<<<ebks, 256, 0, stream>>>(ei, deg);
    k_scan_block<<<nb, 256, 0, stream>>>(deg, rowptr, blocksum, N_NODES);
    k_scan_top<<<1, 256, 0, stream>>>(blocksum, blockoff, nb);
    k_scan_add<<<nb, 256, 0, stream>>>(rowptr, blockoff, cursor, N_NODES);
    k_scatter<<<ebks, 256, 0, stream>>>(ei, cursor, esrc, emeta);

    k_wt<<<HC0, 64, 0, stream>>>(W0, Wt0, IN_F, HC0);
    k_wt<<<HC1, 64, 0, stream>>>(W1, Wt1, HC0, HC1);

    // Layer 0 (reordered: scores from x@W0, aggregate x, then per-head GEMM)
    k_gemm0s<<<gx, 512, 0, stream>>>(xb, Wt0, att_src0, att_dst0, ssrc0, sdst0);
    k_ew<<<ebks, 256, 0, stream>>>(esrc, emeta, ssrc0, sdst0, ae0, l0, ew0);
    k_aggx<<<nodeblk, 256, 0, stream>>>(xb, ew0, rowptr, esrc, aggx);
    k_gemm0b<<<dim3(gx, 4), 256, 0, stream>>>(aggx, Wt0, bias0, out0b);

    // Layer 1
    k_gemm1s<<<gx, 256, 0, stream>>>(out0b, Wt1, att_src1, att_dst1, h1b, ssrc1, sdst1);
    k_ew<<<ebks, 256, 0, stream>>>(esrc, emeta, ssrc1, sdst1, ae1, l1, ew1);
    k_agg1<<<nodeblk, 256, 0, stream>>>(h1b, ew1, rowptr, esrc, bias1, out);
}

// Round 4
// 292.057 us; speedup vs baseline: 1.7820x; 1.3457x over previous
//
#include <hip/hip_runtime.h>
#include <math.h>

#define N_NODES 50000
#define N_EDGES 800000
#define ET (N_EDGES + N_NODES)
#define IN_F 128
#define TDIM 64
#define HEADS 4
#define C0 64
#define C1 16
#define HC0 256
#define HC1 64
#define KF 512 /* fused K = 4*IN_F */
#define SLOPE 0.2f

using short8 = __attribute__((ext_vector_type(8))) short;
using f32x4 = __attribute__((ext_vector_type(4))) float;

__device__ __forceinline__ float bf2f(unsigned u16) { return __uint_as_float(u16 << 16); }
__device__ __forceinline__ unsigned short f2bf(float f) {
    unsigned u = __float_as_uint(f);
    return (unsigned short)((u + 0x7fffu + ((u >> 16) & 1u)) >> 16);
}
__device__ __forceinline__ unsigned pk2(float lo, float hi) {
    return (unsigned)f2bf(lo) | ((unsigned)f2bf(hi) << 16);
}

// ---------------------------------------------------------------------------
// v[td][h] = sum_c lin_e[td][h*C+c] * att_e[h][c]   (one block per td)
__global__ void k_tables(const float* __restrict__ le0, const float* __restrict__ at0,
                         const float* __restrict__ le1, const float* __restrict__ at1,
                         float* __restrict__ v0, float* __restrict__ v1) {
    int td = blockIdx.x;
    int tid = threadIdx.x;  // 256
    int h = tid >> 6, c = tid & 63;
    float p0 = le0[td * HC0 + h * C0 + c] * at0[h * C0 + c];
    for (int m = 1; m < 64; m <<= 1) p0 += __shfl_xor(p0, m);
    if (c == 0) v0[td * 4 + h] = p0;
    float p1 = 0.f;
    if (c < C1) p1 = le1[td * HC1 + h * C1 + c] * at1[h * C1 + c];
    for (int m = 1; m < 16; m <<= 1) p1 += __shfl_xor(p1, m);
    if (c == 0) v1[td * 4 + h] = p1;
}

// l[h] = sum_td v[td][h]  (self-loop logit; edge feature all-ones)
__global__ void k_l(const float* __restrict__ v0, const float* __restrict__ v1,
                    float* __restrict__ l0, float* __restrict__ l1) {
    int tid = threadIdx.x;  // 128
    int w = tid >> 6, l = tid & 63;
    const float4* v = (const float4*)(w ? v1 : v0);
    float4 a = v[l];
    for (int m = 1; m < 64; m <<= 1) {
        a.x += __shfl_xor(a.x, m);
        a.y += __shfl_xor(a.y, m);
        a.z += __shfl_xor(a.z, m);
        a.w += __shfl_xor(a.w, m);
    }
    if (l == 0) ((float4*)(w ? l1 : l0))[0] = a;
}

// Score tables: as0[h][k] = sum_c W0[k][h*64+c]*att_src0[h][c]; ad0 likewise.
__global__ void k_stab(const float* __restrict__ W0, const float* __restrict__ asr,
                       const float* __restrict__ ads, float* __restrict__ as0,
                       float* __restrict__ ad0) {
    int k = blockIdx.x;  // 128
    int tid = threadIdx.x;
    int h = tid >> 6, c = tid & 63;
    float wv = W0[k * HC0 + h * C0 + c];
    float ps = wv * asr[h * C0 + c];
    float pd = wv * ads[h * C0 + c];
    for (int m = 1; m < 64; m <<= 1) {
        ps += __shfl_xor(ps, m);
        pd += __shfl_xor(pd, m);
    }
    if (c == 0) {
        as0[h * IN_F + k] = ps;
        ad0[h * IN_F + k] = pd;
    }
}

// W01t[c1][h*128+k] = bf16( sum_c0 W0[k][h*64+c0] * W1[h*64+c0][c1] )
__global__ void k_w01(const float* __restrict__ W0, const float* __restrict__ W1,
                      unsigned short* __restrict__ W01t) {
    int hk = blockIdx.x;  // 512 = h*128+k
    int h = hk >> 7, k = hk & 127;
    int c1 = threadIdx.x;  // 64
    float acc = 0.f;
    for (int c0 = 0; c0 < C0; ++c0)
        acc += W0[k * HC0 + h * C0 + c0] * W1[(size_t)(h * C0 + c0) * HC1 + c1];
    W01t[(size_t)c1 * KF + hk] = f2bf(acc);
}

// b01[c1] = sum_k bias0[k] * W1[k][c1]
__global__ void k_b01(const float* __restrict__ bias0, const float* __restrict__ W1,
                      float* __restrict__ b01) {
    int c1 = threadIdx.x;  // 64
    float acc = 0.f;
    for (int k = 0; k < HC0; ++k) acc += bias0[k] * W1[(size_t)k * HC1 + c1];
    b01[c1] = acc;
}

// ---------------------------------------------------------------------------
// Fused x->bf16 + layer-0 scores: one wave per node, lane owns 2 channels.
__global__ __launch_bounds__(256) void k_xbs(const float* __restrict__ x,
                                             const float* __restrict__ as0,
                                             const float* __restrict__ ad0,
                                             unsigned short* __restrict__ xb,
                                             float* __restrict__ ssrc, float* __restrict__ sdst) {
    int w = threadIdx.x >> 6, l = threadIdx.x & 63;
    int n = blockIdx.x * 4 + w;
    if (n >= N_NODES) return;
    float2 xv = *(const float2*)(x + (size_t)n * IN_F + l * 2);
    *(unsigned*)(xb + (size_t)n * IN_F + l * 2) = pk2(xv.x, xv.y);
    float ps[4], pd[4];
#pragma unroll
    for (int h = 0; h < 4; ++h) {
        float2 a = *(const float2*)(as0 + h * IN_F + l * 2);
        float2 d = *(const float2*)(ad0 + h * IN_F + l * 2);
        ps[h] = xv.x * a.x + xv.y * a.y;
        pd[h] = xv.x * d.x + xv.y * d.y;
    }
#pragma unroll
    for (int m = 1; m < 64; m <<= 1) {
#pragma unroll
        for (int h = 0; h < 4; ++h) {
            ps[h] += __shfl_xor(ps[h], m);
            pd[h] += __shfl_xor(pd[h], m);
        }
    }
    if (l == 0) {
#pragma unroll
        for (int h = 0; h < 4; ++h) {
            ssrc[n * 4 + h] = ps[h];
            sdst[n * 4 + h] = pd[h];
        }
    }
}

// ---------------------------------------------------------------------------
// CSR build over destination node (shared by both layers)
__global__ void k_count(const int* __restrict__ ei, int* __restrict__ deg) {
    int t = blockIdx.x * blockDim.x + threadIdx.x;
    if (t >= ET) return;
    int d = (t < N_EDGES) ? ei[N_EDGES + t] : (t - N_EDGES);
    atomicAdd(&deg[d], 1);
}

__global__ void k_scan_block(const int* __restrict__ deg, int* __restrict__ rowptr,
                             int* __restrict__ blocksum, int n) {
    __shared__ int buf[256];
    int tid = threadIdx.x, i = blockIdx.x * 256 + tid;
    int v = (i < n) ? deg[i] : 0;
    buf[tid] = v;
    __syncthreads();
    for (int off = 1; off < 256; off <<= 1) {
        int t = (tid >= off) ? buf[tid - off] : 0;
        __syncthreads();
        buf[tid] += t;
        __syncthreads();
    }
    if (i < n) rowptr[i + 1] = buf[tid];
    if (tid == 255) blocksum[blockIdx.x] = buf[255];
}

__global__ void k_scan_top(const int* __restrict__ blocksum, int* __restrict__ blockoff, int nb) {
    __shared__ int buf[256];
    int tid = threadIdx.x;
    int v = (tid < nb) ? blocksum[tid] : 0;
    buf[tid] = v;
    __syncthreads();
    for (int off = 1; off < 256; off <<= 1) {
        int t = (tid >= off) ? buf[tid - off] : 0;
        __syncthreads();
        buf[tid] += t;
        __syncthreads();
    }
    if (tid < nb) blockoff[tid] = buf[tid] - v;  // exclusive
}

__global__ void k_scan_add(int* __restrict__ rowptr, const int* __restrict__ blockoff,
                           int* __restrict__ cursor, int n) {
    int i = blockIdx.x * 256 + threadIdx.x;
    if (i < n) {
        int v = rowptr[i + 1] + blockoff[blockIdx.x];
        rowptr[i + 1] = v;
        cursor[i + 1] = v;
    }
    if (i == 0) {
        rowptr[0] = 0;
        cursor[0] = 0;
    }
}

// Scatter edges into CSR order; also permuted timestamps (-1 = self-loop).
__global__ void k_scatter(const int* __restrict__ ei, const float* __restrict__ ts,
                          int* __restrict__ cursor, int* __restrict__ esrc,
                          int* __restrict__ edst, float* __restrict__ tsp) {
    int t = blockIdx.x * blockDim.x + threadIdx.x;
    if (t >= ET) return;
    int d, s;
    float tv;
    if (t < N_EDGES) {
        s = ei[t];
        d = ei[N_EDGES + t];
        tv = ts[t];
    } else {
        s = t - N_EDGES;
        d = t - N_EDGES;
        tv = -1.f;
    }
    int p = atomicAdd(&cursor[d], 1);
    esrc[p] = s;
    edst[p] = d;
    tsp[p] = tv;
}

// ---------------------------------------------------------------------------
// Permuted time-encode: ae0p/ae1p[p][h] in CSR order; sentinel -> loop logits.
__global__ void k_timeenc(const float* __restrict__ tsp, const float* __restrict__ tw,
                          const float* __restrict__ tb, const float* __restrict__ v0,
                          const float* __restrict__ v1, const float* __restrict__ l0,
                          const float* __restrict__ l1, float* __restrict__ ae0p,
                          float* __restrict__ ae1p) {
    __shared__ float sw[TDIM], sb[TDIM], sv0[TDIM * 4], sv1[TDIM * 4];
    int tid = threadIdx.x;
    if (tid < TDIM) {
        sw[tid] = tw[tid];
        sb[tid] = tb[tid];
    }
    sv0[tid] = v0[tid];
    sv1[tid] = v1[tid];
    __syncthreads();
    int p = blockIdx.x * blockDim.x + tid;
    if (p >= ET) return;
    float time = tsp[p];
    if (time < 0.f) {
        ((float4*)ae0p)[p] = ((const float4*)l0)[0];
        ((float4*)ae1p)[p] = ((const float4*)l1)[0];
        return;
    }
    float a00 = 0, a01 = 0, a02 = 0, a03 = 0, a10 = 0, a11 = 0, a12 = 0, a13 = 0;
#pragma unroll 8
    for (int d = 0; d < TDIM; ++d) {
        float f = fabsf(__cosf(time * sw[d] + sb[d]));
        a00 += f * sv0[d * 4 + 0];
        a01 += f * sv0[d * 4 + 1];
        a02 += f * sv0[d * 4 + 2];
        a03 += f * sv0[d * 4 + 3];
        a10 += f * sv1[d * 4 + 0];
        a11 += f * sv1[d * 4 + 1];
        a12 += f * sv1[d * 4 + 2];
        a13 += f * sv1[d * 4 + 3];
    }
    ((float4*)ae0p)[p] = make_float4(a00, a01, a02, a03);
    ((float4*)ae1p)[p] = make_float4(a10, a11, a12, a13);
}

// ---------------------------------------------------------------------------
// Edge-parallel attention weights (CSR order): ew[p][h]
__global__ void k_ew(const int* __restrict__ esrc, const int* __restrict__ edst,
                     const float* __restrict__ ssrc, const float* __restrict__ sdst,
                     const float* __restrict__ aep, float* __restrict__ ew) {
    int p = blockIdx.x * blockDim.x + threadIdx.x;
    if (p >= ET) return;
    int s = esrc[p], d = edst[p];
    float4 av = ((const float4*)aep)[p];
    float4 sv = ((const float4*)ssrc)[s];
    float4 dv = ((const float4*)sdst)[d];
    float a0 = sv.x + dv.x + av.x;
    float a1 = sv.y + dv.y + av.y;
    float a2 = sv.z + dv.z + av.z;
    float a3 = sv.w + dv.w + av.w;
    a0 = a0 >= 0.f ? a0 : SLOPE * a0;
    a1 = a1 >= 0.f ? a1 : SLOPE * a1;
    a2 = a2 >= 0.f ? a2 : SLOPE * a2;
    a3 = a3 >= 0.f ? a3 : SLOPE * a3;
    ((float4*)ew)[p] = make_float4(__expf(a0), __expf(a1), __expf(a2), __expf(a3));
}

// ---------------------------------------------------------------------------
// Layer-0 aggregation of x: 4 nodes per wave (16-lane groups), lane owns 8 ch.
// aggx[n][h*128+c] = (sum_e e_h * xb[s][c]) / (sum_e e_h)
__global__ __launch_bounds__(256) void k_aggx(const unsigned short* __restrict__ xb,
                                              const float* __restrict__ ew,
                                              const int* __restrict__ rowptr,
                                              const int* __restrict__ esrc,
                                              unsigned short* __restrict__ aggx) {
    int grp = threadIdx.x >> 4, lo = threadIdx.x & 15;
    int n = blockIdx.x * 16 + grp;
    if (n >= N_NODES) return;
    int p0 = rowptr[n], p1 = rowptr[n + 1];
    float acc[4][8];
#pragma unroll
    for (int h = 0; h < 4; ++h)
#pragma unroll
        for (int j = 0; j < 8; ++j) acc[h][j] = 0.f;
    float ss0 = 0, ss1 = 0, ss2 = 0, ss3 = 0;
    for (int p = p0; p < p1; ++p) {
        int s = esrc[p];
        float4 e = ((const float4*)ew)[p];
        uint4 xv = *(const uint4*)(xb + (size_t)s * IN_F + lo * 8);
        float f[8];
        f[0] = bf2f(xv.x & 0xffff);
        f[1] = bf2f(xv.x >> 16);
        f[2] = bf2f(xv.y & 0xffff);
        f[3] = bf2f(xv.y >> 16);
        f[4] = bf2f(xv.z & 0xffff);
        f[5] = bf2f(xv.z >> 16);
        f[6] = bf2f(xv.w & 0xffff);
        f[7] = bf2f(xv.w >> 16);
#pragma unroll
        for (int j = 0; j < 8; ++j) {
            acc[0][j] += e.x * f[j];
            acc[1][j] += e.y * f[j];
            acc[2][j] += e.z * f[j];
            acc[3][j] += e.w * f[j];
        }
        ss0 += e.x;
        ss1 += e.y;
        ss2 += e.z;
        ss3 += e.w;
    }
    float inv[4] = {1.f / (ss0 + 1e-16f), 1.f / (ss1 + 1e-16f), 1.f / (ss2 + 1e-16f),
                    1.f / (ss3 + 1e-16f)};
    size_t base = (size_t)n * KF + lo * 8;
#pragma unroll
    for (int h = 0; h < 4; ++h) {
        uint4 r;
        r.x = pk2(acc[h][0] * inv[h], acc[h][1] * inv[h]);
        r.y = pk2(acc[h][2] * inv[h], acc[h][3] * inv[h]);
        r.z = pk2(acc[h][4] * inv[h], acc[h][5] * inv[h]);
        r.w = pk2(acc[h][6] * inv[h], acc[h][7] * inv[h]);
        *(uint4*)(aggx + base + h * IN_F) = r;
    }
}

// ---------------------------------------------------------------------------
// h1 = aggx @ W01t^T + b01 ; writes h1b (bf16) + fused layer-1 scores.
// Tile 128x64, 4 waves of 32 rows, BK=32, K=512.
__global__ __launch_bounds__(256) void k_gemm1s(
    const unsigned short* __restrict__ A, const unsigned short* __restrict__ Bt,
    const float* __restrict__ b01, const float* __restrict__ a_src,
    const float* __restrict__ a_dst, unsigned short* __restrict__ h1b, float* __restrict__ ssrc,
    float* __restrict__ sdst) {
    __shared__ unsigned short As[128 * 40];
    __shared__ unsigned short Bs[64 * 40];
    int tid = threadIdx.x, w = tid >> 6, l = tid & 63, lo = l & 15, hi = l >> 4;
    int m0 = blockIdx.x * 128;
    f32x4 acc[2][4];
#pragma unroll
    for (int i = 0; i < 2; ++i)
#pragma unroll
        for (int j = 0; j < 4; ++j) acc[i][j] = (f32x4){0.f, 0.f, 0.f, 0.f};
    int arow4 = tid >> 2, aseg = tid & 3;
    for (int k0 = 0; k0 < KF; k0 += 32) {
#pragma unroll
        for (int hf = 0; hf < 2; ++hf) {
            int arow = hf * 64 + arow4;
            uint4 va = {0, 0, 0, 0};
            if (m0 + arow < N_NODES)
                va = *(const uint4*)(A + (size_t)(m0 + arow) * KF + k0 + aseg * 8);
            *(uint4*)&As[arow * 40 + aseg * 8] = va;
        }
        uint4 vb = *(const uint4*)(Bt + (size_t)arow4 * KF + k0 + aseg * 8);
        *(uint4*)&Bs[arow4 * 40 + aseg * 8] = vb;
        __syncthreads();
        short8 af[2], bf[4];
#pragma unroll
        for (int fa = 0; fa < 2; ++fa)
            af[fa] = *(const short8*)&As[(w * 32 + fa * 16 + lo) * 40 + hi * 8];
#pragma unroll
        for (int nf = 0; nf < 4; ++nf) bf[nf] = *(const short8*)&Bs[(nf * 16 + lo) * 40 + hi * 8];
#pragma unroll
        for (int fa = 0; fa < 2; ++fa)
#pragma unroll
            for (int nf = 0; nf < 4; ++nf)
                acc[fa][nf] =
                    __builtin_amdgcn_mfma_f32_16x16x32_bf16(af[fa], bf[nf], acc[fa][nf], 0, 0, 0);
        __syncthreads();
    }
    float asv[4], adv[4], bv[4];
#pragma unroll
    for (int nf = 0; nf < 4; ++nf) {
        asv[nf] = a_src[nf * 16 + lo];
        adv[nf] = a_dst[nf * 16 + lo];
        bv[nf] = b01[nf * 16 + lo];
    }
#pragma unroll
    for (int fa = 0; fa < 2; ++fa)
#pragma unroll
        for (int r = 0; r < 4; ++r) {
            int row = m0 + w * 32 + fa * 16 + hi * 4 + r;
#pragma unroll
            for (int nf = 0; nf < 4; ++nf) {
                float v = acc[fa][nf][r] + bv[nf];
                if (row < N_NODES) h1b[(size_t)row * HC1 + nf * 16 + lo] = f2bf(v);
                float ps = v * asv[nf], pd = v * adv[nf];
                for (int m = 1; m < 16; m <<= 1) {
                    ps += __shfl_xor(ps, m);
                    pd += __shfl_xor(pd, m);
                }
                if (lo == 0 && row < N_NODES) {
                    ssrc[row * 4 + nf] = ps;
                    sdst[row * 4 + nf] = pd;
                }
            }
        }
}

// ---------------------------------------------------------------------------
// Layer-1 aggregation: 4 nodes per wave, lane owns 4 channels of one head.
__global__ __launch_bounds__(256) void k_agg1(const unsigned short* __restrict__ h1b,
                                              const float* __restrict__ ew,
                                              const int* __restrict__ rowptr,
                                              const int* __restrict__ esrc,
                                              const float* __restrict__ bias,
                                              float* __restrict__ out) {
    int grp = threadIdx.x >> 4, lo = threadIdx.x & 15;
    int n = blockIdx.x * 16 + grp;
    if (n >= N_NODES) return;
    int head = lo >> 2;
    int p0 = rowptr[n], p1 = rowptr[n + 1];
    float a0 = 0, a1 = 0, a2 = 0, a3 = 0, ss = 0;
    for (int p = p0; p < p1; ++p) {
        int s = esrc[p];
        float e = ew[p * 4 + head];
        uint2 hv = *(const uint2*)(h1b + (size_t)s * HC1 + lo * 4);
        a0 += e * bf2f(hv.x & 0xffff);
        a1 += e * bf2f(hv.x >> 16);
        a2 += e * bf2f(hv.y & 0xffff);
        a3 += e * bf2f(hv.y >> 16);
        ss += e;
    }
    float inv = 1.f / (ss + 1e-16f);
    float4 b4 = *(const float4*)(bias + lo * 4);
    float4 r = make_float4(a0 * inv + b4.x, a1 * inv + b4.y, a2 * inv + b4.z, a3 * inv + b4.w);
    *(float4*)(out + (size_t)n * HC1 + lo * 4) = r;
}

// ---------------------------------------------------------------------------
extern "C" void kernel_launch(void* const* d_in, const int* in_sizes, int n_in, void* d_out,
                              int out_size, void* d_ws, size_t ws_size, hipStream_t stream) {
    const float* x = (const float*)d_in[0];
    const int* ei = (const int*)d_in[1];
    const float* ts = (const float*)d_in[2];
    const float* time_w = (const float*)d_in[3];
    const float* time_b = (const float*)d_in[4];
    const float* W0 = (const float*)d_in[5];
    const float* att_src0 = (const float*)d_in[6];
    const float* att_dst0 = (const float*)d_in[7];
    const float* lin_edge0 = (const float*)d_in[8];
    const float* att_edge0 = (const float*)d_in[9];
    const float* bias0 = (const float*)d_in[10];
    const float* W1 = (const float*)d_in[11];
    const float* att_src1 = (const float*)d_in[12];
    const float* att_dst1 = (const float*)d_in[13];
    const float* lin_edge1 = (const float*)d_in[14];
    const float* att_edge1 = (const float*)d_in[15];
    const float* bias1 = (const float*)d_in[16];
    float* out = (float*)d_out;

    char* ws = (char*)d_ws;
    size_t off = 0;
    auto alloc = [&](size_t bytes) -> void* {
        void* p = ws + off;
        off = (off + bytes + 255) & ~(size_t)255;
        return p;
    };
    unsigned short* xb = (unsigned short*)alloc((size_t)N_NODES * IN_F * 2);
    unsigned short* aggx = (unsigned short*)alloc((size_t)N_NODES * KF * 2);
    unsigned short* h1b = (unsigned short*)alloc((size_t)N_NODES * HC1 * 2);
    unsigned short* W01t = (unsigned short*)alloc((size_t)HC1 * KF * 2);
    float* b01 = (float*)alloc(HC1 * 4);
    float* as0 = (float*)alloc(4 * IN_F * 4);
    float* ad0 = (float*)alloc(4 * IN_F * 4);
    float* ae0p = (float*)alloc((size_t)ET * 4 * 4);
    float* ae1p = (float*)alloc((size_t)ET * 4 * 4);
    float* ew0 = (float*)alloc((size_t)ET * 4 * 4);
    float* ew1 = (float*)alloc((size_t)ET * 4 * 4);
    float* ssrc0 = (float*)alloc((size_t)N_NODES * 4 * 4);
    float* sdst0 = (float*)alloc((size_t)N_NODES * 4 * 4);
    float* ssrc1 = (float*)alloc((size_t)N_NODES * 4 * 4);
    float* sdst1 = (float*)alloc((size_t)N_NODES * 4 * 4);
    float* v0 = (float*)alloc(TDIM * 4 * 4);
    float* v1 = (float*)alloc(TDIM * 4 * 4);
    float* l0 = (float*)alloc(16);
    float* l1 = (float*)alloc(16);
    float* tsp = (float*)alloc((size_t)ET * 4);
    int* deg = (int*)alloc((size_t)N_NODES * 4);
    int* rowptr = (int*)alloc((size_t)(N_NODES + 1) * 4);
    int* cursor = (int*)alloc((size_t)(N_NODES + 1) * 4);
    int* blocksum = (int*)alloc(256 * 4);
    int* blockoff = (int*)alloc(256 * 4);
    int* esrc = (int*)alloc((size_t)ET * 4);
    int* edst = (int*)alloc((size_t)ET * 4);
    (void)ws_size;
    (void)in_sizes;
    (void)n_in;
    (void)out_size;

    int nb = (N_NODES + 255) / 256;    // 196
    int ebks = (ET + 255) / 256;       // 3321
    int gx = (N_NODES + 127) / 128;    // 391
    int nblk16 = (N_NODES + 15) / 16;  // 3125
    int nblk4 = (N_NODES + 3) / 4;     // 12500

    // Parameter-only precompute
    k_tables<<<TDIM, 256, 0, stream>>>(lin_edge0, att_edge0, lin_edge1, att_edge1, v0, v1);
    k_l<<<1, 128, 0, stream>>>(v0, v1, l0, l1);
    k_stab<<<IN_F, 256, 0, stream>>>(W0, att_src0, att_dst0, as0, ad0);
    k_w01<<<KF, 64, 0, stream>>>(W0, W1, W01t);
    k_b01<<<1, 64, 0, stream>>>(bias0, W1, b01);

    // Node features + layer-0 scores
    k_xbs<<<nblk4, 256, 0, stream>>>(x, as0, ad0, xb, ssrc0, sdst0);

    // CSR
    hipMemsetAsync(deg, 0, (size_t)N_NODES * 4, stream);
    k_count<<<ebks, 256, 0, stream>>>(ei, deg);
    k_scan_block<<<nb, 256, 0, stream>>>(deg, rowptr, blocksum, N_NODES);
    k_scan_top<<<1, 256, 0, stream>>>(blocksum, blockoff, nb);
    k_scan_add<<<nb, 256, 0, stream>>>(rowptr, blockoff, cursor, N_NODES);
    k_scatter<<<ebks, 256, 0, stream>>>(ei, ts, cursor, esrc, edst, tsp);

    // Permuted time encoding
    k_timeenc<<<ebks, 256, 0, stream>>>(tsp, time_w, time_b, v0, v1, l0, l1, ae0p, ae1p);

    // Layer 0: ew -> aggregate x
    k_ew<<<ebks, 256, 0, stream>>>(esrc, edst, ssrc0, sdst0, ae0p, ew0);
    k_aggx<<<nblk16, 256, 0, stream>>>(xb, ew0, rowptr, esrc, aggx);

    // Layer 1: fused GEMM (W0*W1) + scores, ew, aggregate
    k_gemm1s<<<gx, 256, 0, stream>>>(aggx, W01t, b01, att_src1, att_dst1, h1b, ssrc1, sdst1);
    k_ew<<<ebks, 256, 0, stream>>>(esrc, edst, ssrc1, sdst1, ae1p, ew1);
    k_agg1<<<nblk16, 256, 0, stream>>>(h1b, ew1, rowptr, esrc, bias1, out);
}